// Round 1
// baseline (2005.349 us; speedup 1.0000x reference)
//
#include <hip/hip_runtime.h>

#define B_ 16
#define S_ 128
#define T_ 64
#define H_ 128
#define NH_ 8
#define DH_ 16
#define FF_ 256
#define SCALEQK 0.25f

#define EPI_PROJ 0
#define EPI_RELU 1
#define EPI_LNRES 2

// ---------------------------------------------------------------------------
// GEMM + epilogue: out[M,N] = epi(A[M,K] @ W[K,N] + bias [+ resid][LN][relu][pos])
// Block tile 128 rows x 128 cols, 256 threads, thread tile (4+4)x(4+4).
// A staged transposed in LDS so the hot loop reads ds_read_b128.
// ---------------------------------------------------------------------------
template<int K, int EPI, bool PAD, bool FINAL>
__global__ __launch_bounds__(256) void gemm_epi(
    const float* __restrict__ A,
    const float* __restrict__ W,
    const float* __restrict__ bias,
    const float* __restrict__ resid, int rstride,
    const float* __restrict__ lns, const float* __restrict__ lnb,
    const float* __restrict__ pos, const int* __restrict__ lengths,
    float* __restrict__ out, int Ntot)
{
    __shared__ float aT[128 * 132];
    __shared__ float red[128 * 17];
    __shared__ float stat[256];

    const int tid = threadIdx.x;
    const int rg = tid & 15, cg = tid >> 4;
    const size_t rowbase = (size_t)blockIdx.x * 128;
    const int cbase = blockIdx.y * 128;

    float acc[8][8];
#pragma unroll
    for (int i = 0; i < 8; ++i)
#pragma unroll
        for (int j = 0; j < 8; ++j) acc[i][j] = 0.f;

    for (int k0 = 0; k0 < K; k0 += 128) {
        if (k0) __syncthreads();
        for (int idx = tid; idx < 128 * 128; idx += 256) {
            int r = idx >> 7, k = idx & 127;
            size_t row = rowbase + (size_t)r;
            float v;
            if (PAD) {
                int t = (int)(row & 63);
                int n = (int)(row >> 6);
                v = (t < lengths[n]) ? A[row * K + (size_t)(k0 + k)] : -1.0f;
            } else {
                v = A[row * K + (size_t)(k0 + k)];
            }
            aT[k * 132 + r] = v;
        }
        __syncthreads();
        const int r0 = rg * 4, c0 = cg * 4;
#pragma unroll 2
        for (int k = 0; k < 128; ++k) {
            const float* ar = aT + k * 132;
            float4 a0 = *(const float4*)(ar + r0);
            float4 a1 = *(const float4*)(ar + 64 + r0);
            const float* wr = W + (size_t)(k0 + k) * Ntot + cbase;
            float4 b0 = *(const float4*)(wr + c0);
            float4 b1 = *(const float4*)(wr + 64 + c0);
            float av[8] = {a0.x, a0.y, a0.z, a0.w, a1.x, a1.y, a1.z, a1.w};
            float bv[8] = {b0.x, b0.y, b0.z, b0.w, b1.x, b1.y, b1.z, b1.w};
#pragma unroll
            for (int ia = 0; ia < 8; ++ia)
#pragma unroll
                for (int ic = 0; ic < 8; ++ic)
                    acc[ia][ic] = fmaf(av[ia], bv[ic], acc[ia][ic]);
        }
    }

    int rl[8], cl[8];
#pragma unroll
    for (int i = 0; i < 4; ++i) {
        rl[i] = rg * 4 + i; rl[4 + i] = 64 + rg * 4 + i;
        cl[i] = cg * 4 + i; cl[4 + i] = 64 + cg * 4 + i;
    }

    // bias (+ residual)
#pragma unroll
    for (int ia = 0; ia < 8; ++ia)
#pragma unroll
        for (int ic = 0; ic < 8; ++ic) {
            float v = acc[ia][ic] + bias[cbase + cl[ic]];
            if (EPI == EPI_LNRES)
                v += resid[(rowbase + rl[ia]) * (size_t)rstride + cl[ic]];
            acc[ia][ic] = v;
        }

    if (EPI == EPI_RELU) {
#pragma unroll
        for (int ia = 0; ia < 8; ++ia)
#pragma unroll
            for (int ic = 0; ic < 8; ++ic)
                out[(rowbase + rl[ia]) * (size_t)Ntot + cbase + cl[ic]] =
                    fmaxf(acc[ia][ic], 0.f);
        return;
    }

    // LayerNorm over the 128 cols (these launches always have cbase==0, Ntot==128)
    __syncthreads();
#pragma unroll
    for (int ia = 0; ia < 8; ++ia) {
        float p = 0.f;
#pragma unroll
        for (int ic = 0; ic < 8; ++ic) p += acc[ia][ic];
        red[rl[ia] * 17 + cg] = p;
    }
    __syncthreads();
    if (tid < 128) {
        float s = 0.f;
#pragma unroll 4
        for (int c = 0; c < 16; ++c) s += red[tid * 17 + c];
        stat[tid] = s * (1.f / 128.f);
    }
    __syncthreads();
#pragma unroll
    for (int ia = 0; ia < 8; ++ia) {
        float m = stat[rl[ia]];
        float p = 0.f;
#pragma unroll
        for (int ic = 0; ic < 8; ++ic) {
            float d = acc[ia][ic] - m;
            acc[ia][ic] = d;
            p += d * d;
        }
        red[rl[ia] * 17 + cg] = p;
    }
    __syncthreads();
    if (tid < 128) {
        float s = 0.f;
#pragma unroll 4
        for (int c = 0; c < 16; ++c) s += red[tid * 17 + c];
        stat[128 + tid] = rsqrtf(s * (1.f / 128.f) + 1e-5f);
    }
    __syncthreads();
#pragma unroll
    for (int ia = 0; ia < 8; ++ia) {
        size_t row = rowbase + rl[ia];
        float iv = stat[128 + rl[ia]];
#pragma unroll
        for (int ic = 0; ic < 8; ++ic) {
            int c = cl[ic];
            float v = acc[ia][ic] * iv * lns[c] + lnb[c];
            if (EPI == EPI_PROJ)
                v = fmaxf(v, 0.f) + pos[(int)(row & 63) * H_ + c];
            if (FINAL) {
                int b = (int)(row >> 7), s = (int)(row & 127);
                if (s < T_) out[((size_t)(b * T_ + s)) * H_ + c] = v;
            } else {
                out[row * H_ + c] = v;
            }
        }
    }
}

// ---------------------------------------------------------------------------
// Fused attention: per group, compute per-head q,k,v from LDS-transposed x,
// scores + mask + softmax in LDS, o = P @ V written to global [G*LQ, 128].
// MODE 0: temporal full (L=64, LQ=64, prefix-length mask, loop 8 heads)
// MODE 1: temporal single query t=0 (L=64, LQ=1)
// MODE 2: spatial (L=128, LQ=128, validity-bitmask, 1 head per blockIdx.y)
// ---------------------------------------------------------------------------
template<int L, int LQ, int MODE>
__global__ __launch_bounds__(256) void attn_kernel(
    const float* __restrict__ x, float* __restrict__ o,
    const int* __restrict__ lengths,
    const float* __restrict__ Wq, const float* __restrict__ bq,
    const float* __restrict__ Wk, const float* __restrict__ bk,
    const float* __restrict__ Wv, const float* __restrict__ bv)
{
    constexpr int LP = L + 4;
    constexpr int IQT = (LQ < 64) ? LQ : 64;
    constexpr int RT = L / 16;

    __shared__ float xsT[128 * LP];     // x transposed: [j][r]
    __shared__ float qhT[16 * LP];      // [d][i]
    __shared__ float khT[16 * LP];      // [d][j]
    __shared__ float vhT[16 * LP];      // [d][j]
    __shared__ float sc[IQT * LP];      // scores / probs [i][j]
    __shared__ int vld[128];
    __shared__ int lenS;

    const int g = blockIdx.x;
    const int tid = threadIdx.x;
    const float* xg = x + (size_t)g * (L * 128);

    for (int idx = tid; idx < L * 128; idx += 256) {
        int r = idx >> 7, j = idx & 127;
        xsT[j * LP + r] = xg[idx];
    }
    if (MODE == 2) {
        if (tid < 128) vld[tid] = (lengths[g * S_ + tid] > 0) ? 1 : 0;
    } else {
        if (tid == 0) lenS = lengths[g];
    }
    __syncthreads();

    const int h0 = (MODE == 2) ? blockIdx.y : 0;
    const int hN = (MODE == 2) ? h0 + 1 : NH_;

    for (int head = h0; head < hN; ++head) {
        const int hc = head * DH_;
        // ---------- q,k,v projections (register-tiled) ----------
        {
            constexpr int M3 = (MODE == 1) ? 2 : 3;
            if (tid < M3 * 64) {
                const int mat = tid >> 6;
                const int u = tid & 63;
                const int rg = u & 15, cg = u >> 4;
                const float* Wm; const float* bm; float* dst;
                if (MODE == 1) {
                    Wm = mat ? Wv : Wk; bm = mat ? bv : bk; dst = mat ? vhT : khT;
                } else {
                    Wm = (mat == 0) ? Wq : (mat == 1) ? Wk : Wv;
                    bm = (mat == 0) ? bq : (mat == 1) ? bk : bv;
                    dst = (mat == 0) ? qhT : (mat == 1) ? khT : vhT;
                }
                const int r0 = rg * RT, c0 = cg * 4;
                float acc[RT][4];
#pragma unroll
                for (int a = 0; a < RT; ++a)
#pragma unroll
                    for (int b = 0; b < 4; ++b) acc[a][b] = 0.f;
                for (int j = 0; j < 128; ++j) {
                    float4 w4 = *(const float4*)(Wm + j * H_ + hc + c0);
                    const float* xr = xsT + j * LP + r0;
#pragma unroll
                    for (int a4 = 0; a4 < RT; a4 += 4) {
                        float4 x4 = *(const float4*)(xr + a4);
                        float xa[4] = {x4.x, x4.y, x4.z, x4.w};
#pragma unroll
                        for (int a = 0; a < 4; ++a) {
                            acc[a4 + a][0] = fmaf(xa[a], w4.x, acc[a4 + a][0]);
                            acc[a4 + a][1] = fmaf(xa[a], w4.y, acc[a4 + a][1]);
                            acc[a4 + a][2] = fmaf(xa[a], w4.z, acc[a4 + a][2]);
                            acc[a4 + a][3] = fmaf(xa[a], w4.w, acc[a4 + a][3]);
                        }
                    }
                }
#pragma unroll
                for (int a = 0; a < RT; ++a)
#pragma unroll
                    for (int b = 0; b < 4; ++b)
                        dst[(c0 + b) * LP + r0 + a] = acc[a][b] + bm[hc + c0 + b];
            } else if (MODE == 1 && tid >= 128 && tid < 144) {
                const int d = tid - 128;
                float a = bq[hc + d];
                for (int j = 0; j < 128; ++j)
                    a = fmaf(xsT[j * LP], Wq[j * H_ + hc + d], a);
                qhT[d * LP] = a;
            }
        }
        __syncthreads();

        for (int iq0 = 0; iq0 < LQ; iq0 += IQT) {
            // ---------- scores ----------
            if (MODE == 1) {
                if (tid < L) {
                    const int j = tid;
                    float s = 0.f;
#pragma unroll
                    for (int d = 0; d < 16; ++d)
                        s = fmaf(qhT[d * LP], khT[d * LP + j], s);
                    bool valid = (lenS > 0) && (j < lenS);
                    sc[j] = valid ? s * SCALEQK : -1e9f;
                }
            } else {
                const int ig = tid & 15, jg = tid >> 4;
                const int i0 = ig * 4;
                for (int j0 = jg * 4; j0 < L; j0 += 64) {
                    float a[4][4];
#pragma unroll
                    for (int ii = 0; ii < 4; ++ii)
#pragma unroll
                        for (int jj = 0; jj < 4; ++jj) a[ii][jj] = 0.f;
#pragma unroll
                    for (int d = 0; d < 16; ++d) {
                        float4 q4 = *(const float4*)(qhT + d * LP + iq0 + i0);
                        float4 k4 = *(const float4*)(khT + d * LP + j0);
                        float qa[4] = {q4.x, q4.y, q4.z, q4.w};
                        float ka[4] = {k4.x, k4.y, k4.z, k4.w};
#pragma unroll
                        for (int ii = 0; ii < 4; ++ii)
#pragma unroll
                            for (int jj = 0; jj < 4; ++jj)
                                a[ii][jj] = fmaf(qa[ii], ka[jj], a[ii][jj]);
                    }
#pragma unroll
                    for (int ii = 0; ii < 4; ++ii)
#pragma unroll
                        for (int jj = 0; jj < 4; ++jj) {
                            const int i = iq0 + i0 + ii, j = j0 + jj;
                            bool valid;
                            if (MODE == 0) valid = (i < lenS) && (j < lenS);
                            else           valid = (vld[i] != 0) && (vld[j] != 0);
                            sc[(i0 + ii) * LP + j] = valid ? a[ii][jj] * SCALEQK : -1e9f;
                        }
                }
            }
            __syncthreads();
            // ---------- softmax (stable; fully-masked row -> uniform, as ref) ----
            if (MODE == 1) {
                if (tid == 0) {
                    float m = -3.0e38f;
                    for (int j = 0; j < L; ++j) m = fmaxf(m, sc[j]);
                    float s = 0.f;
                    for (int j = 0; j < L; ++j) { float e = __expf(sc[j] - m); sc[j] = e; s += e; }
                    float inv = 1.0f / s;
                    for (int j = 0; j < L; ++j) sc[j] *= inv;
                }
            } else if (tid < IQT) {
                float* srow = sc + tid * LP;
                float m = -3.0e38f;
                for (int jj = 0; jj < L; ++jj) { int j = (jj + tid) & (L - 1); m = fmaxf(m, srow[j]); }
                float s = 0.f;
                for (int jj = 0; jj < L; ++jj) { int j = (jj + tid) & (L - 1); float e = __expf(srow[j] - m); srow[j] = e; s += e; }
                float inv = 1.0f / s;
                for (int jj = 0; jj < L; ++jj) { int j = (jj + tid) & (L - 1); srow[j] *= inv; }
            }
            __syncthreads();
            // ---------- o = P @ V ----------
            if (MODE == 1) {
                if (tid < 16) {
                    const int d = tid;
                    float a = 0.f;
                    for (int j = 0; j < L; ++j) a = fmaf(sc[j], vhT[d * LP + j], a);
                    o[(size_t)g * H_ + hc + d] = a;
                }
            } else {
                const int dg = tid & 7, ig = tid >> 3;   // ig in [0,32)
                const int i0 = ig * 2, d0 = dg * 2;
                float a[2][2] = {{0.f, 0.f}, {0.f, 0.f}};
                for (int j0 = 0; j0 < L; j0 += 4) {
                    float4 p0 = *(const float4*)(sc + (i0 + 0) * LP + j0);
                    float4 p1 = *(const float4*)(sc + (i0 + 1) * LP + j0);
                    float4 v0 = *(const float4*)(vhT + (d0 + 0) * LP + j0);
                    float4 v1 = *(const float4*)(vhT + (d0 + 1) * LP + j0);
                    a[0][0] += p0.x * v0.x + p0.y * v0.y + p0.z * v0.z + p0.w * v0.w;
                    a[0][1] += p0.x * v1.x + p0.y * v1.y + p0.z * v1.z + p0.w * v1.w;
                    a[1][0] += p1.x * v0.x + p1.y * v0.y + p1.z * v0.z + p1.w * v0.w;
                    a[1][1] += p1.x * v1.x + p1.y * v1.y + p1.z * v1.z + p1.w * v1.w;
                }
#pragma unroll
                for (int ii = 0; ii < 2; ++ii)
#pragma unroll
                    for (int dd = 0; dd < 2; ++dd)
                        o[((size_t)g * LQ + iq0 + i0 + ii) * H_ + hc + d0 + dd] = a[ii][dd];
            }
            __syncthreads();
        }
    }
}

// ---------------------------------------------------------------------------
extern "C" void kernel_launch(void* const* d_in, const int* in_sizes, int n_in,
                              void* d_out, int out_size, void* d_ws, size_t ws_size,
                              hipStream_t stream)
{
    const float* poly   = (const float*)d_in[0];
    const int*   lens   = (const int*)d_in[1];
    const float* proj_w = (const float*)d_in[2];
    const float* proj_b = (const float*)d_in[3];
    const float* pls    = (const float*)d_in[4];
    const float* plb    = (const float*)d_in[5];
    const float* pos    = (const float*)d_in[6];
    const float* Wq = (const float*)d_in[7];
    const float* bq = (const float*)d_in[8];
    const float* Wk = (const float*)d_in[9];
    const float* bk = (const float*)d_in[10];
    const float* Wv = (const float*)d_in[11];
    const float* bv = (const float*)d_in[12];
    const float* Wo = (const float*)d_in[13];
    const float* bo = (const float*)d_in[14];
    const float* l1s = (const float*)d_in[15];
    const float* l1b = (const float*)d_in[16];
    const float* W1 = (const float*)d_in[17];
    const float* b1 = (const float*)d_in[18];
    const float* W2 = (const float*)d_in[19];
    const float* b2 = (const float*)d_in[20];
    const float* l2s = (const float*)d_in[21];
    const float* l2b = (const float*)d_in[22];
    float* outp = (float*)d_out;

    float* ws = (float*)d_ws;
    float* xbuf  = ws;                    // [131072,128]  activations (temporal)
    float* obuf  = ws + 16777216;         // [131072,128]  attn-out L0 (aliased by hbuf)
    float* hbuf  = obuf;                  // [65536,256]   FFN hidden, half of L0 rows
    float* o1buf = ws + 33554432;         // [2048,128]    attn-out (L1..L3)
    float* ybuf  = o1buf + 262144;        // [2048,128]    activations (t=0 slice / spatial)
    float* hsml  = ybuf + 262144;         // [2048,256]    FFN hidden small

    const int ROWS0 = B_ * S_ * T_;       // 131072
    const int HALF  = ROWS0 / 2;          // 65536
    const int HH = H_ * H_, HF = H_ * FF_;

    // ---- input MLP: x = relu(LN(pad(poly) @ proj_w + b)) + pos ----
    gemm_epi<128, EPI_PROJ, true, false><<<dim3(ROWS0 / 128, 1), 256, 0, stream>>>(
        poly, proj_w, proj_b, nullptr, 0, pls, plb, pos, lens, xbuf, H_);

    // ---- layer 0: temporal attention, full ----
    attn_kernel<64, 64, 0><<<dim3(2048, 1), 256, 0, stream>>>(
        xbuf, obuf, lens, Wq, bq, Wk, bk, Wv, bv);
    gemm_epi<128, EPI_LNRES, false, false><<<dim3(ROWS0 / 128, 1), 256, 0, stream>>>(
        obuf, Wo, bo, xbuf, H_, l1s, l1b, nullptr, nullptr, xbuf, H_);
    for (int h = 0; h < 2; ++h) {
        float* xh = xbuf + (size_t)h * HALF * H_;
        gemm_epi<128, EPI_RELU, false, false><<<dim3(HALF / 128, 2), 256, 0, stream>>>(
            xh, W1, b1, nullptr, 0, nullptr, nullptr, nullptr, nullptr, hbuf, FF_);
        gemm_epi<256, EPI_LNRES, false, false><<<dim3(HALF / 128, 1), 256, 0, stream>>>(
            hbuf, W2, b2, xh, H_, l2s, l2b, nullptr, nullptr, xh, H_);
    }

    // ---- layer 1: temporal attention, only query t=0 survives downstream ----
    attn_kernel<64, 1, 1><<<dim3(2048, 1), 256, 0, stream>>>(
        xbuf, o1buf, lens, Wq + HH, bq + H_, Wk + HH, bk + H_, Wv + HH, bv + H_);
    gemm_epi<128, EPI_LNRES, false, false><<<dim3(16, 1), 256, 0, stream>>>(
        o1buf, Wo + HH, bo + H_, xbuf, T_ * H_, l1s + H_, l1b + H_, nullptr, nullptr, ybuf, H_);
    gemm_epi<128, EPI_RELU, false, false><<<dim3(16, 2), 256, 0, stream>>>(
        ybuf, W1 + HF, b1 + FF_, nullptr, 0, nullptr, nullptr, nullptr, nullptr, hsml, FF_);
    gemm_epi<256, EPI_LNRES, false, false><<<dim3(16, 1), 256, 0, stream>>>(
        hsml, W2 + HF, b2 + H_, ybuf, H_, l2s + H_, l2b + H_, nullptr, nullptr, ybuf, H_);

    // ---- layers 2,3: spatial attention on the t=0 groups only ----
    for (int li = 2; li < 4; ++li) {
        attn_kernel<128, 128, 2><<<dim3(16, 8), 256, 0, stream>>>(
            ybuf, o1buf, lens,
            Wq + (size_t)li * HH, bq + (size_t)li * H_,
            Wk + (size_t)li * HH, bk + (size_t)li * H_,
            Wv + (size_t)li * HH, bv + (size_t)li * H_);
        gemm_epi<128, EPI_LNRES, false, false><<<dim3(16, 1), 256, 0, stream>>>(
            o1buf, Wo + (size_t)li * HH, bo + (size_t)li * H_, ybuf, H_,
            l1s + (size_t)li * H_, l1b + (size_t)li * H_, nullptr, nullptr, ybuf, H_);
        gemm_epi<128, EPI_RELU, false, false><<<dim3(16, 2), 256, 0, stream>>>(
            ybuf, W1 + (size_t)li * HF, b1 + (size_t)li * FF_,
            nullptr, 0, nullptr, nullptr, nullptr, nullptr, hsml, FF_);
        if (li < 3) {
            gemm_epi<256, EPI_LNRES, false, false><<<dim3(16, 1), 256, 0, stream>>>(
                hsml, W2 + (size_t)li * HF, b2 + (size_t)li * H_, ybuf, H_,
                l2s + (size_t)li * H_, l2b + (size_t)li * H_, nullptr, nullptr, ybuf, H_);
        } else {
            // final FFN: write only the surviving slice out[b, s<64, :]
            gemm_epi<256, EPI_LNRES, false, true><<<dim3(16, 1), 256, 0, stream>>>(
                hsml, W2 + (size_t)li * HF, b2 + (size_t)li * H_, ybuf, H_,
                l2s + (size_t)li * H_, l2b + (size_t)li * H_, nullptr, nullptr, outp, H_);
        }
    }
}

// Round 2
// 581.160 us; speedup vs baseline: 3.4506x; 3.4506x over previous
//
#include <hip/hip_runtime.h>

typedef short short8 __attribute__((ext_vector_type(8)));
typedef float floatx4 __attribute__((ext_vector_type(4)));
typedef unsigned short ushort_t;

#define B_ 16
#define S_ 128
#define T_ 64
#define H_ 128
#define NH_ 8
#define DH_ 16
#define FF_ 256
#define SCALEQK 0.25f

#define EPI_BIAS 0
#define EPI_RELU 1
#define EPI_LNRES 2
#define EPI_PROJ 3

__device__ __forceinline__ float b2f(ushort_t u) {
    union { unsigned int i; float f; } x; x.i = ((unsigned int)u) << 16; return x.f;
}
__device__ __forceinline__ ushort_t f2b(float f) {
    union { float f; unsigned int i; } x; x.f = f;
    unsigned int r = x.i + 0x7fffu + ((x.i >> 16) & 1u);
    return (ushort_t)(r >> 16);
}

// ---------------------------------------------------------------------------
// Weight preconvert: fp32 W[K][N] -> bf16 wT[N][K], via 32x32 LDS tile.
// ---------------------------------------------------------------------------
struct WtEnt { const float* src; int N; int K; int nclog2; int dstoff; };
struct WtArgs { WtEnt e[25]; };

__global__ __launch_bounds__(256) void wt_kernel(WtArgs a, ushort_t* __restrict__ dst) {
    WtEnt ent = a.e[blockIdx.x];
    const int tiles_c = ent.N >> 5;
    const int nt = (ent.K >> 5) * tiles_c;
    const int t = blockIdx.y;
    if (t >= nt) return;
    const int tc = t & (tiles_c - 1);
    const int tr = t >> ent.nclog2;
    __shared__ float ld[32 * 33];
    const int tid = threadIdx.x;
#pragma unroll
    for (int i = 0; i < 4; ++i) {
        int e = tid + i * 256;
        int rr = e >> 5, cc = e & 31;
        ld[rr * 33 + cc] = ent.src[(tr * 32 + rr) * ent.N + tc * 32 + cc];
    }
    __syncthreads();
    ushort_t* d = dst + ent.dstoff;
#pragma unroll
    for (int i = 0; i < 4; ++i) {
        int e = tid + i * 256;
        int rr = e >> 5, cc = e & 31;
        d[(tc * 32 + rr) * ent.K + tr * 32 + cc] = f2b(ld[cc * 33 + rr]);
    }
}

// ---------------------------------------------------------------------------
// MFMA GEMM: out[M,N] = epi(A[M,K] @ W[K,N] + bias ...), W given as bf16 wT[N][K].
// 128x128 block tile, 256 thr = 4 waves, each wave 32 rows x 128 cols
// (2x8 tiles of 16x16x32 bf16 mfma). A converted fp32->bf16 during staging.
// ---------------------------------------------------------------------------
template<int K, int EPI, bool PAD, bool FINAL, bool MULTI, bool OUTB, bool AB16>
__global__ __launch_bounds__(256, 2) void gemm_mfma(
    const void* __restrict__ Av, int lda,
    const ushort_t* wt0, const ushort_t* wt1, const ushort_t* wt2,
    const float* b0, const float* b1, const float* b2,
    const float* __restrict__ resid, int rstride,
    const float* __restrict__ lns, const float* __restrict__ lnb,
    const float* __restrict__ pos, const int* __restrict__ lens,
    void* o0, void* o1, void* o2,
    int Ntot)
{
    __shared__ ushort_t aL[128 * 136];
    __shared__ ushort_t wL[128 * 136];

    const int tid = threadIdx.x;
    const int lane = tid & 63, wv = tid >> 6;
    const size_t rowbase = (size_t)blockIdx.x * 128;

    const ushort_t* wT; const float* bias; void* out; int cbase;
    if (MULTI) {
        int sel = blockIdx.y;
        wT = sel == 0 ? wt0 : (sel == 1 ? wt1 : wt2);
        bias = sel == 0 ? b0 : (sel == 1 ? b1 : b2);
        out = sel == 0 ? o0 : (sel == 1 ? o1 : o2);
        cbase = 0;
    } else {
        wT = wt0; bias = b0; out = o0; cbase = blockIdx.y * 128;
    }

    floatx4 acc[2][8];
#pragma unroll
    for (int a = 0; a < 2; ++a)
#pragma unroll
        for (int c = 0; c < 8; ++c) acc[a][c] = (floatx4){0.f, 0.f, 0.f, 0.f};

    const int arow = wv * 32 + (lane & 15);
    const int koff = (lane >> 4) * 8;

    for (int kc = 0; kc < K; kc += 128) {
        if (kc) __syncthreads();
        // ---- stage A (convert to bf16) ----
#pragma unroll
        for (int it = 0; it < 8; ++it) {
            int e8 = tid + it * 256;
            int row = e8 >> 4, kg = e8 & 15;
            int kk = kc + kg * 8;
            short8 val;
            if (AB16) {
                val = *(const short8*)((const ushort_t*)Av + (size_t)(rowbase + row) * lda + kk);
            } else {
                const float* Af = (const float*)Av + (size_t)(rowbase + row) * lda + kk;
                float f[8];
                *(float4*)(f) = *(const float4*)(Af);
                *(float4*)(f + 4) = *(const float4*)(Af + 4);
                if (PAD) {
                    int r = (int)(rowbase + row);
                    if ((r & 63) >= lens[r >> 6]) {
#pragma unroll
                        for (int q = 0; q < 8; ++q) f[q] = -1.0f;
                    }
                }
#pragma unroll
                for (int q = 0; q < 8; ++q) val[q] = (short)f2b(f[q]);
            }
            *(short8*)&aL[row * 136 + kg * 8] = val;
        }
        // ---- stage W ----
#pragma unroll
        for (int it = 0; it < 8; ++it) {
            int e8 = tid + it * 256;
            int n = e8 >> 4, kg = e8 & 15;
            *(short8*)&wL[n * 136 + kg * 8] =
                *(const short8*)&wT[(size_t)(cbase + n) * K + kc + kg * 8];
        }
        __syncthreads();
        // ---- mfma ----
#pragma unroll
        for (int k0 = 0; k0 < 128; k0 += 32) {
            short8 a0 = *(const short8*)&aL[arow * 136 + k0 + koff];
            short8 a1 = *(const short8*)&aL[(arow + 16) * 136 + k0 + koff];
#pragma unroll
            for (int ct = 0; ct < 8; ++ct) {
                short8 b = *(const short8*)&wL[(ct * 16 + (lane & 15)) * 136 + k0 + koff];
                acc[0][ct] = __builtin_amdgcn_mfma_f32_16x16x32_bf16(a0, b, acc[0][ct], 0, 0, 0);
                acc[1][ct] = __builtin_amdgcn_mfma_f32_16x16x32_bf16(a1, b, acc[1][ct], 0, 0, 0);
            }
        }
    }

    // ---- epilogue ----
    const int col16 = lane & 15;
    const int rgrp = (lane >> 4) * 4;
    float bcol[8], lnsc[8], lnbc[8];
#pragma unroll
    for (int ct = 0; ct < 8; ++ct) bcol[ct] = bias[cbase + ct * 16 + col16];
    if (EPI == EPI_LNRES || EPI == EPI_PROJ) {
#pragma unroll
        for (int ct = 0; ct < 8; ++ct) {
            lnsc[ct] = lns[ct * 16 + col16];
            lnbc[ct] = lnb[ct * 16 + col16];
        }
    }

#pragma unroll
    for (int rt = 0; rt < 2; ++rt) {
        const int rbase = wv * 32 + rt * 16 + rgrp;
#pragma unroll
        for (int ct = 0; ct < 8; ++ct)
#pragma unroll
            for (int rg = 0; rg < 4; ++rg) {
                float v = acc[rt][ct][rg] + bcol[ct];
                if (EPI == EPI_LNRES)
                    v += resid[(rowbase + rbase + rg) * (size_t)rstride + ct * 16 + col16];
                acc[rt][ct][rg] = v;
            }
        if (EPI == EPI_LNRES || EPI == EPI_PROJ) {
            float mean[4], rstd[4];
#pragma unroll
            for (int rg = 0; rg < 4; ++rg) {
                float s = 0.f;
#pragma unroll
                for (int ct = 0; ct < 8; ++ct) s += acc[rt][ct][rg];
                s += __shfl_xor(s, 1); s += __shfl_xor(s, 2);
                s += __shfl_xor(s, 4); s += __shfl_xor(s, 8);
                mean[rg] = s * (1.f / 128.f);
            }
#pragma unroll
            for (int rg = 0; rg < 4; ++rg) {
                float s = 0.f;
#pragma unroll
                for (int ct = 0; ct < 8; ++ct) {
                    float d = acc[rt][ct][rg] - mean[rg];
                    s += d * d;
                }
                s += __shfl_xor(s, 1); s += __shfl_xor(s, 2);
                s += __shfl_xor(s, 4); s += __shfl_xor(s, 8);
                rstd[rg] = rsqrtf(s * (1.f / 128.f) + 1e-5f);
            }
#pragma unroll
            for (int ct = 0; ct < 8; ++ct)
#pragma unroll
                for (int rg = 0; rg < 4; ++rg)
                    acc[rt][ct][rg] = (acc[rt][ct][rg] - mean[rg]) * rstd[rg] * lnsc[ct] + lnbc[ct];
        }
#pragma unroll
        for (int ct = 0; ct < 8; ++ct)
#pragma unroll
            for (int rg = 0; rg < 4; ++rg) {
                size_t grow = rowbase + rbase + rg;
                int col = cbase + ct * 16 + col16;
                float v = acc[rt][ct][rg];
                if (EPI == EPI_RELU) v = fmaxf(v, 0.f);
                if (EPI == EPI_PROJ)
                    v = fmaxf(v, 0.f) + pos[((int)grow & 63) * H_ + ct * 16 + col16];
                if (FINAL) {
                    int b = (int)(grow >> 7), s = (int)(grow & 127);
                    if (s < T_) ((float*)out)[((size_t)(b * T_ + s)) * H_ + col] = v;
                } else if (OUTB) {
                    ((ushort_t*)out)[grow * (size_t)Ntot + col] = f2b(v);
                } else {
                    ((float*)out)[grow * (size_t)Ntot + col] = v;
                }
            }
    }
}

// ---------------------------------------------------------------------------
// Temporal attention (scores+softmax+PV), L=64. Block = (group, head-half).
// 256 thr = 4 heads x 64 rows; K/V (4 heads' dims) staged fp32 in LDS;
// all LDS reads are wave-broadcast (wave == one head). o aliases q (same elems).
// ---------------------------------------------------------------------------
__global__ __launch_bounds__(256, 2) void attn_t(
    ushort_t* qo, const ushort_t* __restrict__ kk, const ushort_t* __restrict__ vv,
    const int* __restrict__ lens)
{
    __shared__ float kL[64 * 68];
    __shared__ float vL[64 * 68];
    const int tid = threadIdx.x;
    const int g = blockIdx.x;
    const int hh = blockIdx.y;
    const size_t rowg = (size_t)g * 64;
    const int len = lens[g];

#pragma unroll
    for (int it = 0; it < 2; ++it) {
        int e8 = tid + it * 256;
        int j = e8 >> 3, dg = e8 & 7;
        short8 k8 = *(const short8*)&kk[(rowg + j) * 128 + hh * 64 + dg * 8];
        short8 v8 = *(const short8*)&vv[(rowg + j) * 128 + hh * 64 + dg * 8];
        float* kd = &kL[j * 68 + dg * 8];
        float* vd = &vL[j * 68 + dg * 8];
#pragma unroll
        for (int q = 0; q < 8; ++q) { kd[q] = b2f((ushort_t)k8[q]); vd[q] = b2f((ushort_t)v8[q]); }
    }
    __syncthreads();

    const int hl = tid >> 6;
    const int i = tid & 63;
    const int hc = hl * 16;
    const int h = hh * 4 + hl;

    float qf[16];
    {
        const short8* qp = (const short8*)&qo[(rowg + i) * 128 + h * 16];
        short8 q0 = qp[0], q1 = qp[1];
#pragma unroll
        for (int q = 0; q < 8; ++q) { qf[q] = b2f((ushort_t)q0[q]); qf[8 + q] = b2f((ushort_t)q1[q]); }
    }

    float sc[64];
    const bool iv = (i < len);
#pragma unroll
    for (int j = 0; j < 64; ++j) {
        const float* kr = &kL[j * 68 + hc];
        float s = 0.f;
#pragma unroll
        for (int d = 0; d < 16; ++d) s = fmaf(qf[d], kr[d], s);
        sc[j] = (iv && (j < len)) ? s * SCALEQK : -1e9f;
    }
    float m = -3.0e38f;
#pragma unroll
    for (int j = 0; j < 64; ++j) m = fmaxf(m, sc[j]);
    float sum = 0.f;
#pragma unroll
    for (int j = 0; j < 64; ++j) { float e = __expf(sc[j] - m); sc[j] = e; sum += e; }
    const float inv = 1.0f / sum;
    float of[16];
#pragma unroll
    for (int d = 0; d < 16; ++d) of[d] = 0.f;
#pragma unroll
    for (int j = 0; j < 64; ++j) {
        float p = sc[j] * inv;
        const float* vr = &vL[j * 68 + hc];
#pragma unroll
        for (int d = 0; d < 16; ++d) of[d] = fmaf(p, vr[d], of[d]);
    }
    short8 o0v, o1v;
#pragma unroll
    for (int q = 0; q < 8; ++q) { o0v[q] = (short)f2b(of[q]); o1v[q] = (short)f2b(of[8 + q]); }
    short8* op = (short8*)&qo[(rowg + i) * 128 + h * 16];
    op[0] = o0v; op[1] = o1v;
}

// ---------------------------------------------------------------------------
// Spatial attention, L=128. Block = (b-group, head-pair). 256 thr = 2 heads x 128 rows.
// ---------------------------------------------------------------------------
__global__ __launch_bounds__(256, 1) void attn_s(
    ushort_t* qo, const ushort_t* __restrict__ kk, const ushort_t* __restrict__ vv,
    const int* __restrict__ lens)
{
    __shared__ float kL[128 * 36];
    __shared__ float vL[128 * 36];
    __shared__ int vldL[128];
    const int tid = threadIdx.x;
    const int b = blockIdx.x, hp = blockIdx.y;
    const size_t rowg = (size_t)b * 128;

    if (tid < 128) vldL[tid] = (lens[b * 128 + tid] > 0) ? 1 : 0;
#pragma unroll
    for (int it = 0; it < 2; ++it) {
        int e8 = tid + it * 256;
        int j = e8 >> 2, dg = e8 & 3;
        short8 k8 = *(const short8*)&kk[(rowg + j) * 128 + hp * 32 + dg * 8];
        short8 v8 = *(const short8*)&vv[(rowg + j) * 128 + hp * 32 + dg * 8];
        float* kd = &kL[j * 36 + dg * 8];
        float* vd = &vL[j * 36 + dg * 8];
#pragma unroll
        for (int q = 0; q < 8; ++q) { kd[q] = b2f((ushort_t)k8[q]); vd[q] = b2f((ushort_t)v8[q]); }
    }
    __syncthreads();

    const int hl = tid >> 7;
    const int i = tid & 127;
    const int hc = hl * 16;
    const int h = hp * 2 + hl;

    float qf[16];
    {
        const short8* qp = (const short8*)&qo[(rowg + i) * 128 + h * 16];
        short8 q0 = qp[0], q1 = qp[1];
#pragma unroll
        for (int q = 0; q < 8; ++q) { qf[q] = b2f((ushort_t)q0[q]); qf[8 + q] = b2f((ushort_t)q1[q]); }
    }

    float sc[128];
    const bool iv = vldL[i] != 0;
#pragma unroll
    for (int j = 0; j < 128; ++j) {
        const float* kr = &kL[j * 36 + hc];
        float s = 0.f;
#pragma unroll
        for (int d = 0; d < 16; ++d) s = fmaf(qf[d], kr[d], s);
        sc[j] = (iv && vldL[j]) ? s * SCALEQK : -1e9f;
    }
    float m = -3.0e38f;
#pragma unroll
    for (int j = 0; j < 128; ++j) m = fmaxf(m, sc[j]);
    float sum = 0.f;
#pragma unroll
    for (int j = 0; j < 128; ++j) { float e = __expf(sc[j] - m); sc[j] = e; sum += e; }
    const float inv = 1.0f / sum;
    float of[16];
#pragma unroll
    for (int d = 0; d < 16; ++d) of[d] = 0.f;
#pragma unroll
    for (int j = 0; j < 128; ++j) {
        float p = sc[j] * inv;
        const float* vr = &vL[j * 36 + hc];
#pragma unroll
        for (int d = 0; d < 16; ++d) of[d] = fmaf(p, vr[d], of[d]);
    }
    short8 o0v, o1v;
#pragma unroll
    for (int q = 0; q < 8; ++q) { o0v[q] = (short)f2b(of[q]); o1v[q] = (short)f2b(of[8 + q]); }
    short8* op = (short8*)&qo[(rowg + i) * 128 + h * 16];
    op[0] = o0v; op[1] = o1v;
}

// ---------------------------------------------------------------------------
// L1 single-query attention: per group, q = row t=0 only. 256 thr = 8 heads x 32.
// ---------------------------------------------------------------------------
__global__ __launch_bounds__(256) void attn_q1(
    const ushort_t* __restrict__ q1, const ushort_t* __restrict__ kk,
    const ushort_t* __restrict__ vv, const int* __restrict__ lens,
    ushort_t* __restrict__ o1)
{
    __shared__ float ps[8 * 64];
    const int tid = threadIdx.x;
    const int g = blockIdx.x;
    const size_t rowg = (size_t)g * 64;
    const int len = lens[g];
    const int h = tid >> 5, l = tid & 31;

    float qf[16];
    {
        const short8* qp = (const short8*)&q1[(size_t)g * 128 + h * 16];
        short8 q0 = qp[0], q1v = qp[1];
#pragma unroll
        for (int q = 0; q < 8; ++q) { qf[q] = b2f((ushort_t)q0[q]); qf[8 + q] = b2f((ushort_t)q1v[q]); }
    }
    float s[2];
#pragma unroll
    for (int half = 0; half < 2; ++half) {
        int j = l + half * 32;
        const short8* kp = (const short8*)&kk[(rowg + j) * 128 + h * 16];
        short8 k0 = kp[0], k1 = kp[1];
        float a = 0.f;
#pragma unroll
        for (int q = 0; q < 8; ++q) a = fmaf(qf[q], b2f((ushort_t)k0[q]), a);
#pragma unroll
        for (int q = 0; q < 8; ++q) a = fmaf(qf[8 + q], b2f((ushort_t)k1[q]), a);
        s[half] = ((len > 0) && (j < len)) ? a * SCALEQK : -1e9f;
    }
    float m = fmaxf(s[0], s[1]);
#pragma unroll
    for (int d = 1; d < 32; d <<= 1) m = fmaxf(m, __shfl_xor(m, d));
    float e0 = __expf(s[0] - m), e1 = __expf(s[1] - m);
    float sum = e0 + e1;
#pragma unroll
    for (int d = 1; d < 32; d <<= 1) sum += __shfl_xor(sum, d);
    const float inv = 1.0f / sum;
    ps[h * 64 + l] = e0 * inv;
    ps[h * 64 + l + 32] = e1 * inv;
    __syncthreads();
    if (l < 16) {
        float a = 0.f;
        for (int j = 0; j < 64; ++j)
            a = fmaf(ps[h * 64 + j], b2f(vv[(rowg + j) * 128 + h * 16 + l]), a);
        o1[(size_t)g * 128 + h * 16 + l] = f2b(a);
    }
}

// ---------------------------------------------------------------------------
extern "C" void kernel_launch(void* const* d_in, const int* in_sizes, int n_in,
                              void* d_out, int out_size, void* d_ws, size_t ws_size,
                              hipStream_t stream)
{
    const float* poly   = (const float*)d_in[0];
    const int*   lens   = (const int*)d_in[1];
    const float* proj_w = (const float*)d_in[2];
    const float* proj_b = (const float*)d_in[3];
    const float* pls    = (const float*)d_in[4];
    const float* plb    = (const float*)d_in[5];
    const float* pos    = (const float*)d_in[6];
    const float* Wq = (const float*)d_in[7];
    const float* bq = (const float*)d_in[8];
    const float* Wk = (const float*)d_in[9];
    const float* bk = (const float*)d_in[10];
    const float* Wv = (const float*)d_in[11];
    const float* bv = (const float*)d_in[12];
    const float* Wo = (const float*)d_in[13];
    const float* bo = (const float*)d_in[14];
    const float* l1s = (const float*)d_in[15];
    const float* l1b = (const float*)d_in[16];
    const float* W1 = (const float*)d_in[17];
    const float* b1 = (const float*)d_in[18];
    const float* W2 = (const float*)d_in[19];
    const float* b2 = (const float*)d_in[20];
    const float* l2s = (const float*)d_in[21];
    const float* l2b = (const float*)d_in[22];
    float* outp = (float*)d_out;

    char* base = (char*)d_ws;
    ushort_t* wt   = (ushort_t*)base;                       // 540672 bf16 = 1,081,344 B
    float* xbuf    = (float*)(base + 1081344);              // [131072,128] fp32
    ushort_t* qbuf = (ushort_t*)(base + 68190208);          // [65536,128] bf16
    ushort_t* kbuf = (ushort_t*)(base + 84967424);          // [65536,128] bf16
    ushort_t* vbuf = (ushort_t*)(base + 101744640);         // [65536,128] bf16
    ushort_t* hbuf = kbuf;                                  // [65536,256] bf16 (aliases k|v)
    ushort_t* q1buf= (ushort_t*)(base + 118521856);         // [1024,128] bf16
    ushort_t* o1buf= (ushort_t*)(base + 118784000);         // [2048,128] bf16
    float* ybuf    = (float*)(base + 119308288);            // [2048,128] fp32
    ushort_t* hsml = (ushort_t*)(base + 120356864);         // [2048,256] bf16
    ushort_t* q2   = (ushort_t*)(base + 121405440);         // [2048,128] bf16
    ushort_t* k2   = (ushort_t*)(base + 121929728);
    ushort_t* v2   = (ushort_t*)(base + 122454016);

    const int HH = H_ * H_, HF = H_ * FF_;

    // wT offsets (ushort units)
    const int offP = 0;
    auto offQ = [&](int l) { return 16384 + l * 4 * 16384 + 0 * 16384; };
    auto offK = [&](int l) { return 16384 + l * 4 * 16384 + 1 * 16384; };
    auto offV = [&](int l) { return 16384 + l * 4 * 16384 + 2 * 16384; };
    auto offO = [&](int l) { return 16384 + l * 4 * 16384 + 3 * 16384; };
    auto offW1 = [&](int l) { return 278528 + l * 65536; };
    auto offW2 = [&](int l) { return 278528 + l * 65536 + 32768; };

    WtArgs wa;
    wa.e[0] = {proj_w, 128, 128, 2, offP};
    for (int l = 0; l < 4; ++l) {
        wa.e[1 + l * 4 + 0] = {Wq + l * HH, 128, 128, 2, offQ(l)};
        wa.e[1 + l * 4 + 1] = {Wk + l * HH, 128, 128, 2, offK(l)};
        wa.e[1 + l * 4 + 2] = {Wv + l * HH, 128, 128, 2, offV(l)};
        wa.e[1 + l * 4 + 3] = {Wo + l * HH, 128, 128, 2, offO(l)};
    }
    for (int l = 0; l < 4; ++l) {
        wa.e[17 + l * 2 + 0] = {W1 + l * HF, 256, 128, 3, offW1(l)};
        wa.e[17 + l * 2 + 1] = {W2 + l * HF, 128, 256, 2, offW2(l)};
    }
    wt_kernel<<<dim3(25, 32), 256, 0, stream>>>(wa, wt);

    // ---- input MLP: x = relu(LN(pad(poly)@proj_w + b)) + pos ----
    gemm_mfma<128, EPI_PROJ, true, false, false, false, false><<<dim3(1024, 1), 256, 0, stream>>>(
        poly, 128, wt + offP, wt + offP, wt + offP, proj_b, proj_b, proj_b,
        nullptr, 0, pls, plb, pos, lens, xbuf, xbuf, xbuf, H_);

    // ---- layer 0 (temporal), two 65536-row halves ----
    for (int hf = 0; hf < 2; ++hf) {
        float* xh = xbuf + (size_t)hf * 65536 * 128;
        const int* lh = lens + hf * 1024;
        gemm_mfma<128, EPI_BIAS, false, false, true, true, false><<<dim3(512, 3), 256, 0, stream>>>(
            xh, 128, wt + offQ(0), wt + offK(0), wt + offV(0), bq, bk, bv,
            nullptr, 0, nullptr, nullptr, nullptr, nullptr, qbuf, kbuf, vbuf, H_);
        attn_t<<<dim3(1024, 2), 256, 0, stream>>>(qbuf, kbuf, vbuf, lh);
        gemm_mfma<128, EPI_LNRES, false, false, false, false, true><<<dim3(512, 1), 256, 0, stream>>>(
            qbuf, 128, wt + offO(0), wt + offO(0), wt + offO(0), bo, bo, bo,
            xh, 128, l1s, l1b, nullptr, nullptr, xh, xh, xh, H_);
        gemm_mfma<128, EPI_RELU, false, false, false, true, false><<<dim3(512, 2), 256, 0, stream>>>(
            xh, 128, wt + offW1(0), wt + offW1(0), wt + offW1(0), b1, b1, b1,
            nullptr, 0, nullptr, nullptr, nullptr, nullptr, hbuf, hbuf, hbuf, FF_);
        gemm_mfma<256, EPI_LNRES, false, false, false, false, true><<<dim3(512, 1), 256, 0, stream>>>(
            hbuf, 256, wt + offW2(0), wt + offW2(0), wt + offW2(0), b2, b2, b2,
            xh, 128, l2s, l2b, nullptr, nullptr, xh, xh, xh, H_);
    }

    // ---- layer 1 (temporal, only t=0 queries survive) ----
    for (int hf = 0; hf < 2; ++hf) {
        float* xh = xbuf + (size_t)hf * 65536 * 128;
        const int* lh = lens + hf * 1024;
        gemm_mfma<128, EPI_BIAS, false, false, true, true, false><<<dim3(512, 2), 256, 0, stream>>>(
            xh, 128, wt + offK(1), wt + offV(1), wt + offV(1), bk + H_, bv + H_, bv + H_,
            nullptr, 0, nullptr, nullptr, nullptr, nullptr, kbuf, vbuf, vbuf, H_);
        gemm_mfma<128, EPI_BIAS, false, false, false, true, false><<<dim3(8, 1), 256, 0, stream>>>(
            xh, 64 * 128, wt + offQ(1), wt + offQ(1), wt + offQ(1), bq + H_, bq + H_, bq + H_,
            nullptr, 0, nullptr, nullptr, nullptr, nullptr, q1buf, q1buf, q1buf, H_);
        attn_q1<<<dim3(1024, 1), 256, 0, stream>>>(q1buf, kbuf, vbuf, lh,
                                                   o1buf + (size_t)hf * 1024 * 128);
    }
    gemm_mfma<128, EPI_LNRES, false, false, false, false, true><<<dim3(16, 1), 256, 0, stream>>>(
        o1buf, 128, wt + offO(1), wt + offO(1), wt + offO(1), bo + H_, bo + H_, bo + H_,
        xbuf, 64 * 128, l1s + H_, l1b + H_, nullptr, nullptr, ybuf, ybuf, ybuf, H_);
    gemm_mfma<128, EPI_RELU, false, false, false, true, false><<<dim3(16, 2), 256, 0, stream>>>(
        ybuf, 128, wt + offW1(1), wt + offW1(1), wt + offW1(1), b1 + FF_, b1 + FF_, b1 + FF_,
        nullptr, 0, nullptr, nullptr, nullptr, nullptr, hsml, hsml, hsml, FF_);
    gemm_mfma<256, EPI_LNRES, false, false, false, false, true><<<dim3(16, 1), 256, 0, stream>>>(
        hsml, 256, wt + offW2(1), wt + offW2(1), wt + offW2(1), b2 + H_, b2 + H_, b2 + H_,
        ybuf, 128, l2s + H_, l2b + H_, nullptr, nullptr, ybuf, ybuf, ybuf, H_);

    // ---- layers 2,3 (spatial, t=0 groups only: [2048,128]) ----
    for (int l = 2; l < 4; ++l) {
        gemm_mfma<128, EPI_BIAS, false, false, true, true, false><<<dim3(16, 3), 256, 0, stream>>>(
            ybuf, 128, wt + offQ(l), wt + offK(l), wt + offV(l), bq + l * H_, bk + l * H_, bv + l * H_,
            nullptr, 0, nullptr, nullptr, nullptr, nullptr, q2, k2, v2, H_);
        attn_s<<<dim3(16, 4), 256, 0, stream>>>(q2, k2, v2, lens);
        gemm_mfma<128, EPI_LNRES, false, false, false, false, true><<<dim3(16, 1), 256, 0, stream>>>(
            q2, 128, wt + offO(l), wt + offO(l), wt + offO(l), bo + l * H_, bo + l * H_, bo + l * H_,
            ybuf, 128, l1s + l * H_, l1b + l * H_, nullptr, nullptr, ybuf, ybuf, ybuf, H_);
        gemm_mfma<128, EPI_RELU, false, false, false, true, false><<<dim3(16, 2), 256, 0, stream>>>(
            ybuf, 128, wt + offW1(l), wt + offW1(l), wt + offW1(l), b1 + l * FF_, b1 + l * FF_, b1 + l * FF_,
            nullptr, 0, nullptr, nullptr, nullptr, nullptr, hsml, hsml, hsml, FF_);
        if (l < 3) {
            gemm_mfma<256, EPI_LNRES, false, false, false, false, true><<<dim3(16, 1), 256, 0, stream>>>(
                hsml, 256, wt + offW2(l), wt + offW2(l), wt + offW2(l), b2 + l * H_, b2 + l * H_, b2 + l * H_,
                ybuf, 128, l2s + l * H_, l2b + l * H_, nullptr, nullptr, ybuf, ybuf, ybuf, H_);
        } else {
            gemm_mfma<256, EPI_LNRES, false, true, false, false, true><<<dim3(16, 1), 256, 0, stream>>>(
                hsml, 256, wt + offW2(l), wt + offW2(l), wt + offW2(l), b2 + l * H_, b2 + l * H_, b2 + l * H_,
                ybuf, 128, l2s + l * H_, l2b + l * H_, nullptr, nullptr, outp, outp, outp, H_);
        }
    }
}

// Round 5
// 471.625 us; speedup vs baseline: 4.2520x; 1.2322x over previous
//
#include <hip/hip_runtime.h>

typedef short short8 __attribute__((ext_vector_type(8)));
typedef short short4_t __attribute__((ext_vector_type(4)));
typedef float floatx4 __attribute__((ext_vector_type(4)));
typedef unsigned short ushort_t;

#define B_ 16
#define S_ 128
#define T_ 64
#define H_ 128
#define FF_ 256
#define SCALEQK 0.25f

// bf16 transposed-weight pool offsets (ushort units)
#define OFFP 0
#define OFFQ(l) (16384 + (l) * 65536)
#define OFFK(l) (OFFQ(l) + 16384)
#define OFFV(l) (OFFQ(l) + 32768)
#define OFFO(l) (OFFQ(l) + 49152)
#define OFFW1(l) (278528 + (l) * 65536)
#define OFFW2(l) (OFFW1(l) + 32768)

__device__ __forceinline__ float b2f(ushort_t u) {
    union { unsigned int i; float f; } x; x.i = ((unsigned int)u) << 16; return x.f;
}
__device__ __forceinline__ ushort_t f2b(float f) {
    union { float f; unsigned int i; } x; x.f = f;
    unsigned int r = x.i + 0x7fffu + ((x.i >> 16) & 1u);
    return (ushort_t)(r >> 16);
}
__device__ __forceinline__ int pack2b(float a, float b) {
    return (int)f2b(a) | ((int)f2b(b) << 16);
}

// ---------------------------------------------------------------------------
// Weight preconvert: fp32 W[K][N] -> bf16 wT[N][K] (round-2 proven).
// ---------------------------------------------------------------------------
struct WtEnt { const float* src; int N; int K; int nclog2; int dstoff; };
struct WtArgs { WtEnt e[25]; };

__global__ __launch_bounds__(256) void wt_kernel(WtArgs a, ushort_t* __restrict__ dst) {
    WtEnt ent = a.e[blockIdx.x];
    const int tiles_c = ent.N >> 5;
    const int nt = (ent.K >> 5) * tiles_c;
    const int t = blockIdx.y;
    if (t >= nt) return;
    const int tc = t & (tiles_c - 1);
    const int tr = t >> ent.nclog2;
    __shared__ float ld[32 * 33];
    const int tid = threadIdx.x;
#pragma unroll
    for (int i = 0; i < 4; ++i) {
        int e = tid + i * 256;
        int rr = e >> 5, cc = e & 31;
        ld[rr * 33 + cc] = ent.src[(tr * 32 + rr) * ent.N + tc * 32 + cc];
    }
    __syncthreads();
    ushort_t* d = dst + ent.dstoff;
#pragma unroll
    for (int i = 0; i < 4; ++i) {
        int e = tid + i * 256;
        int rr = e >> 5, cc = e & 31;
        d[(tc * 32 + rr) * ent.K + tr * 32 + cc] = f2b(ld[cc * 33 + rr]);
    }
}

// ---------------------------------------------------------------------------
// Core: col-split MFMA gemm. Wave w covers cols [colbase, colbase+CT*16) of all
// RT*16 rows. A from LDS bf16 (stride sa), W as global bf16 wT[N][KK] (L2-hot).
// ---------------------------------------------------------------------------
template<int RT, int CT, int KK>
__device__ __forceinline__ void mm_g(const ushort_t* aL, int sa,
                                     const ushort_t* __restrict__ wT,
                                     int colbase, int lane, floatx4 (&acc)[RT][CT]) {
    const int l15 = lane & 15, lq8 = (lane >> 4) * 8;
#pragma unroll
    for (int r = 0; r < RT; ++r)
#pragma unroll
        for (int c = 0; c < CT; ++c) acc[r][c] = (floatx4){0.f, 0.f, 0.f, 0.f};
#pragma unroll
    for (int k0 = 0; k0 < KK; k0 += 32) {
        short8 b[CT];
#pragma unroll
        for (int c = 0; c < CT; ++c)
            b[c] = *(const short8*)&wT[(colbase + c * 16 + l15) * KK + k0 + lq8];
#pragma unroll
        for (int r = 0; r < RT; ++r) {
            short8 a = *(const short8*)&aL[(r * 16 + l15) * sa + k0 + lq8];
#pragma unroll
            for (int c = 0; c < CT; ++c)
                acc[r][c] = __builtin_amdgcn_mfma_f32_16x16x32_bf16(a, b[c], acc[r][c], 0, 0, 0);
        }
    }
}

template<int RT, int CT>
__device__ __forceinline__ void add_bias(floatx4 (&acc)[RT][CT], const float* b,
                                         int colbase, int l15) {
#pragma unroll
    for (int c = 0; c < CT; ++c) {
        float bc = b[colbase + c * 16 + l15];
#pragma unroll
        for (int r = 0; r < RT; ++r)
#pragma unroll
            for (int g = 0; g < 4; ++g) acc[r][c][g] += bc;
    }
}

// fp32 register residual stream helpers (same thread->elem map across phases)
template<int RT, int CT>
__device__ __forceinline__ void add_resid_reg(floatx4 (&acc)[RT][CT],
                                              const float (&res)[RT][CT][4]) {
#pragma unroll
    for (int r = 0; r < RT; ++r)
#pragma unroll
        for (int c = 0; c < CT; ++c)
#pragma unroll
            for (int g = 0; g < 4; ++g) acc[r][c][g] += res[r][c][g];
}
template<int RT, int CT>
__device__ __forceinline__ void save_resid(float (&res)[RT][CT][4],
                                           const floatx4 (&acc)[RT][CT]) {
#pragma unroll
    for (int r = 0; r < RT; ++r)
#pragma unroll
        for (int c = 0; c < CT; ++c)
#pragma unroll
            for (int g = 0; g < 4; ++g) res[r][c][g] = acc[r][c][g];
}

// normal store: dst[row][col] bf16
template<int RT, int CT>
__device__ __forceinline__ void st_n(const floatx4 (&acc)[RT][CT], ushort_t* dst, int stride,
                                     int colbase, int l15, int lq) {
#pragma unroll
    for (int r = 0; r < RT; ++r)
#pragma unroll
        for (int g = 0; g < 4; ++g) {
            int row = r * 16 + lq * 4 + g;
#pragma unroll
            for (int c = 0; c < CT; ++c)
                dst[row * stride + colbase + c * 16 + l15] = f2b(acc[r][c][g]);
        }
}

// transposed store: dst[col][row] bf16 (b64-packed over the 4 regs = 4 rows)
template<int RT, int CT>
__device__ __forceinline__ void st_t(const floatx4 (&acc)[RT][CT], ushort_t* dst, int stride,
                                     int colbase, int l15, int lq) {
#pragma unroll
    for (int r = 0; r < RT; ++r)
#pragma unroll
        for (int c = 0; c < CT; ++c) {
            int d = colbase + c * 16 + l15;
            short4_t p;
#pragma unroll
            for (int g = 0; g < 4; ++g) p[g] = (short)f2b(acc[r][c][g]);
            *(short4_t*)&dst[d * stride + r * 16 + lq * 4] = p;
        }
}

// LayerNorm over 128 cols, cross-wave via redL (float[M*8]): one barrier.
template<int RT, int CT>
__device__ __forceinline__ void ln_norm(floatx4 (&acc)[RT][CT], float* redL,
                                        const float* lns, const float* lnb,
                                        int colbase, int l15, int lq, int wv) {
#pragma unroll
    for (int r = 0; r < RT; ++r)
#pragma unroll
        for (int g = 0; g < 4; ++g) {
            float s = 0.f, q = 0.f;
#pragma unroll
            for (int c = 0; c < CT; ++c) { float v = acc[r][c][g]; s += v; q += v * v; }
            s += __shfl_xor(s, 1); s += __shfl_xor(s, 2); s += __shfl_xor(s, 4); s += __shfl_xor(s, 8);
            q += __shfl_xor(q, 1); q += __shfl_xor(q, 2); q += __shfl_xor(q, 4); q += __shfl_xor(q, 8);
            if (l15 == 0) {
                int row = r * 16 + lq * 4 + g;
                redL[row * 8 + wv] = s;
                redL[row * 8 + 4 + wv] = q;
            }
        }
    __syncthreads();
#pragma unroll
    for (int r = 0; r < RT; ++r)
#pragma unroll
        for (int g = 0; g < 4; ++g) {
            int row = r * 16 + lq * 4 + g;
            float4 S = *(float4*)&redL[row * 8];
            float4 Q = *(float4*)&redL[row * 8 + 4];
            float mean = (S.x + S.y + S.z + S.w) * (1.f / 128.f);
            float var = (Q.x + Q.y + Q.z + Q.w) * (1.f / 128.f) - mean * mean;
            float rstd = rsqrtf(var + 1e-5f);
#pragma unroll
            for (int c = 0; c < CT; ++c) {
                int col = colbase + c * 16 + l15;
                acc[r][c][g] = (acc[r][c][g] - mean) * rstd * lns[col] + lnb[col];
            }
        }
}

// softmax on S^T tiles (C-layout), mask, normalize, pack to bf16 pairs.
template<int JT>
__device__ __forceinline__ void softmax_pack(floatx4 (&st)[JT], bool iv, unsigned jm,
                                             int (&px)[JT][2]) {
    float ev[JT][4];
    float mx = -3.0e38f;
#pragma unroll
    for (int jt = 0; jt < JT; ++jt)
#pragma unroll
        for (int g = 0; g < 4; ++g) {
            bool ok = iv && ((jm >> (jt * 4 + g)) & 1u);
            float s = ok ? st[jt][g] * SCALEQK : -1e9f;
            ev[jt][g] = s; mx = fmaxf(mx, s);
        }
    mx = fmaxf(mx, __shfl_xor(mx, 16)); mx = fmaxf(mx, __shfl_xor(mx, 32));
    float sum = 0.f;
#pragma unroll
    for (int jt = 0; jt < JT; ++jt)
#pragma unroll
        for (int g = 0; g < 4; ++g) { float e = __expf(ev[jt][g] - mx); ev[jt][g] = e; sum += e; }
    sum += __shfl_xor(sum, 16); sum += __shfl_xor(sum, 32);
    float inv = 1.f / sum;
#pragma unroll
    for (int jt = 0; jt < JT; ++jt) {
        px[jt][0] = pack2b(ev[jt][0] * inv, ev[jt][1] * inv);
        px[jt][1] = pack2b(ev[jt][2] * inv, ev[jt][3] * inv);
    }
}

// Build x32 B-frag from softmax registers via lane shuffle.
// FIX (R5): __shfl evaluates its operand on the SOURCE lane, so the tile
// index must be lane-uniform inside the shuffle. Shuffle both candidate
// tiles, select by the target's tsel afterwards.
__device__ __forceinline__ short8 pfrag(const int (*px)[2], int jc, int lq, int l15) {
    const int jA = (lq & 1) * 32 + l15;
    int a0 = __shfl(px[jc * 2][0], jA);
    int a1 = __shfl(px[jc * 2][1], jA);
    int a2 = __shfl(px[jc * 2][0], jA + 16);
    int a3 = __shfl(px[jc * 2][1], jA + 16);
    int b0 = __shfl(px[jc * 2 + 1][0], jA);
    int b1 = __shfl(px[jc * 2 + 1][1], jA);
    int b2 = __shfl(px[jc * 2 + 1][0], jA + 16);
    int b3 = __shfl(px[jc * 2 + 1][1], jA + 16);
    const bool t = (lq >> 1) != 0;
    union { int4 i; short8 s; } u;
    u.i = make_int4(t ? b0 : a0, t ? b1 : a1, t ? b2 : a2, t ? b3 : a3);
    return u.s;
}
__device__ __forceinline__ short8 vfrag(const ushort_t* vT, int stride, int row, int off) {
    int2 a = *(const int2*)&vT[row * stride + off];
    int2 b = *(const int2*)&vT[row * stride + off + 4];
    union { int4 i; short8 s; } u;
    u.i = make_int4(a.x, a.y, b.x, b.y);
    return u.s;
}

// ---------------------------------------------------------------------------
// K1: per group g (64 rows): input proj -> L0 full -> L1 (kv + q@t0 + attn).
// Residual stream kept in fp32 registers (xre); bf16 LDS copy feeds MFMA only.
// Writes o1[g][128] (bf16) and xr0f[g][128] (fp32). 2048 blocks.
// ---------------------------------------------------------------------------
__global__ __launch_bounds__(256, 2) void k1_mega(
    const float* __restrict__ poly, const int* __restrict__ lens,
    const ushort_t* __restrict__ wt,
    const float* __restrict__ projb, const float* __restrict__ pls,
    const float* __restrict__ plb, const float* __restrict__ pos,
    const float* __restrict__ bq0, const float* __restrict__ bk0,
    const float* __restrict__ bv0, const float* __restrict__ bo0,
    const float* __restrict__ l1s0, const float* __restrict__ l1b0,
    const float* __restrict__ b10, const float* __restrict__ b20,
    const float* __restrict__ l2s0, const float* __restrict__ l2b0,
    const float* __restrict__ bq1, const float* __restrict__ bk1,
    const float* __restrict__ bv1,
    ushort_t* __restrict__ o1, float* __restrict__ xr0f)
{
    __shared__ ushort_t pool[34816];
    __shared__ float redL[512];
    __shared__ float psL[8 * 68];
    __shared__ float q1L[128];
    ushort_t* xL = pool;            // [64][136]
    ushort_t* qL = pool + 8704;     // [64][136]  (o written in-place per head)
    ushort_t* kL = pool + 17408;    // [64][136]
    ushort_t* vT = pool + 26112;    // [128][68]  v transposed
    ushort_t* hL = pool + 17408;    // [64][272]  FFN hidden, overlays kL+vT

    const int tid = threadIdx.x, lane = tid & 63, wv = tid >> 6;
    const int l15 = lane & 15, lq = lane >> 4;
    const int g = blockIdx.x;
    const int len = lens[g];

    // ---- stage poly -> xL (bf16, -1 pad) ----
    {
        const float* pg = poly + (size_t)g * 8192;
#pragma unroll
        for (int it = 0; it < 8; ++it) {
            int e4 = (tid + it * 256) * 4;
            int row = e4 >> 7, col = e4 & 127;
            float4 f = *(const float4*)(pg + e4);
            if (row >= len) { f.x = -1.f; f.y = -1.f; f.z = -1.f; f.w = -1.f; }
            short4_t u;
            u[0] = (short)f2b(f.x); u[1] = (short)f2b(f.y);
            u[2] = (short)f2b(f.z); u[3] = (short)f2b(f.w);
            *(short4_t*)&xL[row * 136 + col] = u;
        }
    }
    __syncthreads();

    floatx4 a2[4][2];
    float xre[4][2][4];             // fp32 residual stream (this thread's slice)

    // ---- P1: input proj + LN + relu + pos -> xre, xL ----
    mm_g<4, 2, 128>(xL, 136, wt + OFFP, wv * 32, lane, a2);
    add_bias<4, 2>(a2, projb, wv * 32, l15);
    ln_norm<4, 2>(a2, redL, pls, plb, wv * 32, l15, lq, wv);
    __syncthreads();               // done reading xL (staged poly) before overwrite
#pragma unroll
    for (int r = 0; r < 4; ++r)
#pragma unroll
        for (int gg = 0; gg < 4; ++gg) {
            int row = r * 16 + lq * 4 + gg;
#pragma unroll
            for (int c = 0; c < 2; ++c) {
                int col = wv * 32 + c * 16 + l15;
                float v = fmaxf(a2[r][c][gg], 0.f) + pos[row * 128 + col];
                xre[r][c][gg] = v;
                xL[row * 136 + col] = f2b(v);
            }
        }
    __syncthreads();

    // ---- P2: L0 QKV ----
    mm_g<4, 2, 128>(xL, 136, wt + OFFQ(0), wv * 32, lane, a2);
    add_bias<4, 2>(a2, bq0, wv * 32, l15);
    st_n<4, 2>(a2, qL, 136, wv * 32, l15, lq);
    mm_g<4, 2, 128>(xL, 136, wt + OFFK(0), wv * 32, lane, a2);
    add_bias<4, 2>(a2, bk0, wv * 32, l15);
    st_n<4, 2>(a2, kL, 136, wv * 32, l15, lq);
    mm_g<4, 2, 128>(xL, 136, wt + OFFV(0), wv * 32, lane, a2);
    add_bias<4, 2>(a2, bv0, wv * 32, l15);
    st_t<4, 2>(a2, vT, 68, wv * 32, l15, lq);
    __syncthreads();

    // ---- P3: L0 attention (MFMA S^T, reg softmax, shuffle-PV) ----
    {
        const int iRow = wv * 16 + l15;
        const bool iv = iRow < len;
        unsigned jm = 0;
#pragma unroll
        for (int jt = 0; jt < 4; ++jt)
#pragma unroll
            for (int gg = 0; gg < 4; ++gg)
                if (jt * 16 + lq * 4 + gg < len) jm |= (1u << (jt * 4 + gg));
        for (int h = 0; h < 8; ++h) {
            const int hc = h * 16;
            short8 z8 = {0, 0, 0, 0, 0, 0, 0, 0};
            short8 bqf = z8;
            if (lq < 2) bqf = *(const short8*)&qL[iRow * 136 + hc + lq * 8];
            floatx4 st[4];
#pragma unroll
            for (int jt = 0; jt < 4; ++jt) {
                short8 ak = z8;
                if (lq < 2) ak = *(const short8*)&kL[(jt * 16 + l15) * 136 + hc + lq * 8];
                floatx4 zz = {0.f, 0.f, 0.f, 0.f};
                st[jt] = __builtin_amdgcn_mfma_f32_16x16x32_bf16(ak, bqf, zz, 0, 0, 0);
            }
            int px[4][2];
            softmax_pack<4>(st, iv, jm, px);
            floatx4 ao = {0.f, 0.f, 0.f, 0.f};
#pragma unroll
            for (int jc = 0; jc < 2; ++jc) {
                short8 av = vfrag(vT, 68, hc + l15, jc * 32 + lq * 8);
                short8 bp = pfrag(px, jc, lq, l15);
                ao = __builtin_amdgcn_mfma_f32_16x16x32_bf16(av, bp, ao, 0, 0, 0);
            }
            short4_t w;
#pragma unroll
            for (int gg = 0; gg < 4; ++gg) w[gg] = (short)f2b(ao[gg]);
            *(short4_t*)&qL[iRow * 136 + hc + lq * 4] = w;
        }
    }
    __syncthreads();

    // ---- P4: O-proj + resid + LN -> xre, xL ----
    mm_g<4, 2, 128>(qL, 136, wt + OFFO(0), wv * 32, lane, a2);
    add_bias<4, 2>(a2, bo0, wv * 32, l15);
    add_resid_reg<4, 2>(a2, xre);
    ln_norm<4, 2>(a2, redL, l1s0, l1b0, wv * 32, l15, lq, wv);
    save_resid<4, 2>(xre, a2);
    st_n<4, 2>(a2, xL, 136, wv * 32, l15, lq);
    __syncthreads();

    // ---- P5: FFN W1 + relu -> hL ----
    {
        floatx4 a4[4][4];
        mm_g<4, 4, 128>(xL, 136, wt + OFFW1(0), wv * 64, lane, a4);
        add_bias<4, 4>(a4, b10, wv * 64, l15);
#pragma unroll
        for (int r = 0; r < 4; ++r)
#pragma unroll
            for (int c = 0; c < 4; ++c)
#pragma unroll
                for (int gg = 0; gg < 4; ++gg) a4[r][c][gg] = fmaxf(a4[r][c][gg], 0.f);
        st_n<4, 4>(a4, hL, 272, wv * 64, l15, lq);
    }
    __syncthreads();

    // ---- P6: FFN W2 + resid + LN -> xre, xL; row0 -> xr0f (fp32) ----
    mm_g<4, 2, 256>(hL, 272, wt + OFFW2(0), wv * 32, lane, a2);
    add_bias<4, 2>(a2, b20, wv * 32, l15);
    add_resid_reg<4, 2>(a2, xre);
    ln_norm<4, 2>(a2, redL, l2s0, l2b0, wv * 32, l15, lq, wv);
    save_resid<4, 2>(xre, a2);
    st_n<4, 2>(a2, xL, 136, wv * 32, l15, lq);
    if (lq == 0) {
#pragma unroll
        for (int c = 0; c < 2; ++c)
            xr0f[(size_t)g * 128 + wv * 32 + c * 16 + l15] = a2[0][c][0];   // row 0
    }
    __syncthreads();

    // ---- P7: L1 K,V (full) + q at t=0 ----
    mm_g<4, 2, 128>(xL, 136, wt + OFFK(1), wv * 32, lane, a2);
    add_bias<4, 2>(a2, bk1, wv * 32, l15);
    st_n<4, 2>(a2, kL, 136, wv * 32, l15, lq);
    mm_g<4, 2, 128>(xL, 136, wt + OFFV(1), wv * 32, lane, a2);
    add_bias<4, 2>(a2, bv1, wv * 32, l15);
    st_t<4, 2>(a2, vT, 68, wv * 32, l15, lq);
    if (tid < 128) {
        int d = tid;
        float a = bq1[d];
        const ushort_t* wq = wt + OFFQ(1) + d * 128;
#pragma unroll 4
        for (int j0 = 0; j0 < 128; j0 += 8) {
            short8 w8 = *(const short8*)&wq[j0];
            short8 x8 = *(const short8*)&xL[j0];
#pragma unroll
            for (int q = 0; q < 8; ++q)
                a = fmaf(b2f((ushort_t)x8[q]), b2f((ushort_t)w8[q]), a);
        }
        q1L[d] = a;
    }
    __syncthreads();

    // ---- P8: L1 single-query attention -> o1 ----
    {
        int h = tid >> 5, jj = tid & 31;
        int hc = h * 16;
        float s[2];
#pragma unroll
        for (int half = 0; half < 2; ++half) {
            int j = jj + half * 32;
            float a = 0.f;
            short8 k0v = *(const short8*)&kL[j * 136 + hc];
            short8 k1v = *(const short8*)&kL[j * 136 + hc + 8];
#pragma unroll
            for (int q = 0; q < 8; ++q) {
                a = fmaf(q1L[hc + q], b2f((ushort_t)k0v[q]), a);
                a = fmaf(q1L[hc + 8 + q], b2f((ushort_t)k1v[q]), a);
            }
            s[half] = (j < len) ? a * SCALEQK : -1e9f;
        }
        float mx = fmaxf(s[0], s[1]);
#pragma unroll
        for (int d = 1; d < 32; d <<= 1) mx = fmaxf(mx, __shfl_xor(mx, d));
        float e0 = __expf(s[0] - mx), e1 = __expf(s[1] - mx);
        float sum = e0 + e1;
#pragma unroll
        for (int d = 1; d < 32; d <<= 1) sum += __shfl_xor(sum, d);
        float inv = 1.f / sum;
        psL[h * 68 + jj] = e0 * inv;
        psL[h * 68 + jj + 32] = e1 * inv;
    }
    __syncthreads();
    if (tid < 128) {
        int h = tid >> 4, d = tid & 15, hc = h * 16;
        float a = 0.f;
#pragma unroll 4
        for (int j0 = 0; j0 < 64; j0 += 4) {
            float4 p4 = *(const float4*)&psL[h * 68 + j0];
            short4_t v4 = *(const short4_t*)&vT[(hc + d) * 68 + j0];
            a += p4.x * b2f((ushort_t)v4[0]) + p4.y * b2f((ushort_t)v4[1])
               + p4.z * b2f((ushort_t)v4[2]) + p4.w * b2f((ushort_t)v4[3]);
        }
        o1[(size_t)g * 128 + hc + d] = f2b(a);
    }
}

// ---------------------------------------------------------------------------
// K2: tail per b (16 blocks, 128 rows): L1 o-proj+LN+FFN, spatial layers 2,3,
// final slice write. Residual stream fp32 in registers (yre).
// ---------------------------------------------------------------------------
__global__ __launch_bounds__(256, 1) void k2_tail(
    const int* __restrict__ lens, const ushort_t* __restrict__ wt,
    const ushort_t* __restrict__ o1, const float* __restrict__ xr0f,
    const float* __restrict__ bq, const float* __restrict__ bk,
    const float* __restrict__ bv, const float* __restrict__ bo,
    const float* __restrict__ l1s, const float* __restrict__ l1b,
    const float* __restrict__ b1, const float* __restrict__ b2,
    const float* __restrict__ l2s, const float* __restrict__ l2b,
    float* __restrict__ outp)
{
    __shared__ ushort_t pool[69632];
    __shared__ float redL[1024];
    __shared__ int vld[128];
    ushort_t* yL = pool;             // [128][136]
    ushort_t* qL = pool + 17408;     // [128][136] (o in-place)
    ushort_t* kL = pool + 34816;     // [128][136]
    ushort_t* vT = pool + 52224;     // [128][136] transposed
    ushort_t* hL = pool + 34816;     // [128][272] overlays kL+vT

    const int tid = threadIdx.x, lane = tid & 63, wv = tid >> 6;
    const int l15 = lane & 15, lq = lane >> 4;
    const int b = blockIdx.x;

    if (tid < 128) vld[tid] = (lens[b * 128 + tid] > 0) ? 1 : 0;
    // stage o1 block rows -> kL
#pragma unroll
    for (int it = 0; it < 8; ++it) {
        int e = tid + it * 256;
        int row = e >> 4, cg = e & 15;
        *(short8*)&kL[row * 136 + cg * 8] =
            *(const short8*)&o1[((size_t)b * 128 + row) * 128 + cg * 8];
    }
    __syncthreads();

    floatx4 a2[8][2];
    float yre[8][2][4];

    // ---- L1 o-proj + resid(global fp32 xr0f) + LN -> yre, yL ----
    mm_g<8, 2, 128>(kL, 136, wt + OFFO(1), wv * 32, lane, a2);
    add_bias<8, 2>(a2, bo + 128, wv * 32, l15);
#pragma unroll
    for (int r = 0; r < 8; ++r)
#pragma unroll
        for (int gg = 0; gg < 4; ++gg) {
            int row = r * 16 + lq * 4 + gg;
#pragma unroll
            for (int c = 0; c < 2; ++c)
                a2[r][c][gg] += xr0f[((size_t)b * 128 + row) * 128 + wv * 32 + c * 16 + l15];
        }
    ln_norm<8, 2>(a2, redL, l1s + 128, l1b + 128, wv * 32, l15, lq, wv);
    save_resid<8, 2>(yre, a2);
    st_n<8, 2>(a2, yL, 136, wv * 32, l15, lq);
    __syncthreads();
    // ---- L1 FFN ----
    {
        floatx4 a4[8][4];
        mm_g<8, 4, 128>(yL, 136, wt + OFFW1(1), wv * 64, lane, a4);
        add_bias<8, 4>(a4, b1 + FF_, wv * 64, l15);
#pragma unroll
        for (int r = 0; r < 8; ++r)
#pragma unroll
            for (int c = 0; c < 4; ++c)
#pragma unroll
                for (int gg = 0; gg < 4; ++gg) a4[r][c][gg] = fmaxf(a4[r][c][gg], 0.f);
        st_n<8, 4>(a4, hL, 272, wv * 64, l15, lq);
    }
    __syncthreads();
    mm_g<8, 2, 256>(hL, 272, wt + OFFW2(1), wv * 32, lane, a2);
    add_bias<8, 2>(a2, b2 + 128, wv * 32, l15);
    add_resid_reg<8, 2>(a2, yre);
    ln_norm<8, 2>(a2, redL, l2s + 128, l2b + 128, wv * 32, l15, lq, wv);
    save_resid<8, 2>(yre, a2);
    st_n<8, 2>(a2, yL, 136, wv * 32, l15, lq);
    __syncthreads();

    // j-validity bitmask for this lane (same for both spatial layers)
    unsigned jm = 0;
#pragma unroll
    for (int jt = 0; jt < 8; ++jt)
#pragma unroll
        for (int gg = 0; gg < 4; ++gg)
            if (vld[jt * 16 + lq * 4 + gg]) jm |= (1u << (jt * 4 + gg));
    const int i0 = wv * 32 + l15, i1 = i0 + 16;
    const bool iv0 = vld[i0] != 0, iv1 = vld[i1] != 0;

    // ---- spatial layers 2,3 ----
    for (int l = 2; l < 4; ++l) {
        // QKV
        mm_g<8, 2, 128>(yL, 136, wt + OFFQ(l), wv * 32, lane, a2);
        add_bias<8, 2>(a2, bq + l * 128, wv * 32, l15);
        st_n<8, 2>(a2, qL, 136, wv * 32, l15, lq);
        mm_g<8, 2, 128>(yL, 136, wt + OFFK(l), wv * 32, lane, a2);
        add_bias<8, 2>(a2, bk + l * 128, wv * 32, l15);
        st_n<8, 2>(a2, kL, 136, wv * 32, l15, lq);
        mm_g<8, 2, 128>(yL, 136, wt + OFFV(l), wv * 32, lane, a2);
        add_bias<8, 2>(a2, bv + l * 128, wv * 32, l15);
        st_t<8, 2>(a2, vT, 136, wv * 32, l15, lq);
        __syncthreads();
        // attention
        for (int h = 0; h < 8; ++h) {
            const int hc = h * 16;
            short8 z8 = {0, 0, 0, 0, 0, 0, 0, 0};
            short8 bqa = z8, bqb = z8;
            if (lq < 2) {
                bqa = *(const short8*)&qL[i0 * 136 + hc + lq * 8];
                bqb = *(const short8*)&qL[i1 * 136 + hc + lq * 8];
            }
            floatx4 s0[8], s1[8];
#pragma unroll
            for (int jt = 0; jt < 8; ++jt) {
                short8 ak = z8;
                if (lq < 2) ak = *(const short8*)&kL[(jt * 16 + l15) * 136 + hc + lq * 8];
                floatx4 zz = {0.f, 0.f, 0.f, 0.f};
                s0[jt] = __builtin_amdgcn_mfma_f32_16x16x32_bf16(ak, bqa, zz, 0, 0, 0);
                s1[jt] = __builtin_amdgcn_mfma_f32_16x16x32_bf16(ak, bqb, zz, 0, 0, 0);
            }
            int px0[8][2], px1[8][2];
            softmax_pack<8>(s0, iv0, jm, px0);
            softmax_pack<8>(s1, iv1, jm, px1);
            floatx4 o0 = {0.f, 0.f, 0.f, 0.f}, o1a = {0.f, 0.f, 0.f, 0.f};
#pragma unroll
            for (int jc = 0; jc < 4; ++jc) {
                short8 av = vfrag(vT, 136, hc + l15, jc * 32 + lq * 8);
                o0 = __builtin_amdgcn_mfma_f32_16x16x32_bf16(av, pfrag(px0, jc, lq, l15), o0, 0, 0, 0);
                o1a = __builtin_amdgcn_mfma_f32_16x16x32_bf16(av, pfrag(px1, jc, lq, l15), o1a, 0, 0, 0);
            }
            short4_t w0, w1;
#pragma unroll
            for (int gg = 0; gg < 4; ++gg) { w0[gg] = (short)f2b(o0[gg]); w1[gg] = (short)f2b(o1a[gg]); }
            *(short4_t*)&qL[i0 * 136 + hc + lq * 4] = w0;
            *(short4_t*)&qL[i1 * 136 + hc + lq * 4] = w1;
        }
        __syncthreads();
        // O-proj + resid + LN -> yre, yL
        mm_g<8, 2, 128>(qL, 136, wt + OFFO(l), wv * 32, lane, a2);
        add_bias<8, 2>(a2, bo + l * 128, wv * 32, l15);
        add_resid_reg<8, 2>(a2, yre);
        ln_norm<8, 2>(a2, redL, l1s + l * 128, l1b + l * 128, wv * 32, l15, lq, wv);
        save_resid<8, 2>(yre, a2);
        st_n<8, 2>(a2, yL, 136, wv * 32, l15, lq);
        __syncthreads();
        // FFN
        {
            floatx4 a4[8][4];
            mm_g<8, 4, 128>(yL, 136, wt + OFFW1(l), wv * 64, lane, a4);
            add_bias<8, 4>(a4, b1 + l * FF_, wv * 64, l15);
#pragma unroll
            for (int r = 0; r < 8; ++r)
#pragma unroll
                for (int c = 0; c < 4; ++c)
#pragma unroll
                    for (int gg = 0; gg < 4; ++gg) a4[r][c][gg] = fmaxf(a4[r][c][gg], 0.f);
            st_n<8, 4>(a4, hL, 272, wv * 64, l15, lq);
        }
        __syncthreads();
        mm_g<8, 2, 256>(hL, 272, wt + OFFW2(l), wv * 32, lane, a2);
        add_bias<8, 2>(a2, b2 + l * 128, wv * 32, l15);
        add_resid_reg<8, 2>(a2, yre);
        ln_norm<8, 2>(a2, redL, l2s + l * 128, l2b + l * 128, wv * 32, l15, lq, wv);
        if (l == 3) {
#pragma unroll
            for (int r = 0; r < 4; ++r)     // only rows < 64 survive
#pragma unroll
                for (int gg = 0; gg < 4; ++gg) {
                    int row = r * 16 + lq * 4 + gg;
#pragma unroll
                    for (int c = 0; c < 2; ++c)
                        outp[(size_t)b * 8192 + row * 128 + wv * 32 + c * 16 + l15] = a2[r][c][gg];
                }
        } else {
            save_resid<8, 2>(yre, a2);
            st_n<8, 2>(a2, yL, 136, wv * 32, l15, lq);
        }
        __syncthreads();
    }
}

// ---------------------------------------------------------------------------
extern "C" void kernel_launch(void* const* d_in, const int* in_sizes, int n_in,
                              void* d_out, int out_size, void* d_ws, size_t ws_size,
                              hipStream_t stream)
{
    const float* poly   = (const float*)d_in[0];
    const int*   lens   = (const int*)d_in[1];
    const float* proj_w = (const float*)d_in[2];
    const float* proj_b = (const float*)d_in[3];
    const float* pls    = (const float*)d_in[4];
    const float* plb    = (const float*)d_in[5];
    const float* pos    = (const float*)d_in[6];
    const float* Wq = (const float*)d_in[7];
    const float* bq = (const float*)d_in[8];
    const float* Wk = (const float*)d_in[9];
    const float* bk = (const float*)d_in[10];
    const float* Wv = (const float*)d_in[11];
    const float* bv = (const float*)d_in[12];
    const float* Wo = (const float*)d_in[13];
    const float* bo = (const float*)d_in[14];
    const float* l1s = (const float*)d_in[15];
    const float* l1b = (const float*)d_in[16];
    const float* W1 = (const float*)d_in[17];
    const float* b1 = (const float*)d_in[18];
    const float* W2 = (const float*)d_in[19];
    const float* b2 = (const float*)d_in[20];
    const float* l2s = (const float*)d_in[21];
    const float* l2b = (const float*)d_in[22];
    float* outp = (float*)d_out;

    char* base = (char*)d_ws;
    ushort_t* wt    = (ushort_t*)base;                 // 540672 bf16
    ushort_t* o1buf = (ushort_t*)(base + 1081344);     // [2048][128] bf16
    float* xr0f     = (float*)(base + 1605632);        // [2048][128] fp32

    const int HH = H_ * H_, HF = H_ * FF_;
    WtArgs wa;
    wa.e[0] = {proj_w, 128, 128, 2, OFFP};
    for (int l = 0; l < 4; ++l) {
        wa.e[1 + l * 4 + 0] = {Wq + l * HH, 128, 128, 2, OFFQ(l)};
        wa.e[1 + l * 4 + 1] = {Wk + l * HH, 128, 128, 2, OFFK(l)};
        wa.e[1 + l * 4 + 2] = {Wv + l * HH, 128, 128, 2, OFFV(l)};
        wa.e[1 + l * 4 + 3] = {Wo + l * HH, 128, 128, 2, OFFO(l)};
    }
    for (int l = 0; l < 4; ++l) {
        wa.e[17 + l * 2 + 0] = {W1 + l * HF, 256, 128, 3, OFFW1(l)};
        wa.e[17 + l * 2 + 1] = {W2 + l * HF, 128, 256, 2, OFFW2(l)};
    }
    wt_kernel<<<dim3(25, 32), 256, 0, stream>>>(wa, wt);

    k1_mega<<<dim3(2048), 256, 0, stream>>>(
        poly, lens, wt,
        proj_b, pls, plb, pos,
        bq, bk, bv, bo, l1s, l1b, b1, b2, l2s, l2b,
        bq + H_, bk + H_, bv + H_,
        o1buf, xr0f);

    k2_tail<<<dim3(16), 256, 0, stream>>>(
        lens, wt, o1buf, xr0f,
        bq, bk, bv, bo, l1s, l1b, b1, b2, l2s, l2b,
        outp);
}